// Round 2
// baseline (844.010 us; speedup 1.0000x reference)
//
#include <hip/hip_runtime.h>
#include <hip/hip_bf16.h>
#include <math.h>

#define VTAG 50257
#define EDIM 128
#define NREP 10
#define BFUNC 2048
#define NSTRIP 786          // ceil(50257/64)
#define NPAD (NSTRIP * 64)  // 50304

typedef __bf16 bf16x8 __attribute__((ext_vector_type(8)));
typedef float f32x4 __attribute__((ext_vector_type(4)));

__device__ __forceinline__ unsigned short f2bf(float x) {
    unsigned u = __float_as_uint(x);
    unsigned r = (u + 0x7fffu + ((u >> 16) & 1u)) >> 16;
    return (unsigned short)r;
}

// ---------------------------------------------------------------------------
// K1: per-function context encode + attention pool -> v (bf16) [B, E]
// block = 128 threads = 2 waves; each WAVE handles one function.
// lane ln covers channels e0=ln and e1=ln+64 (halves LDS broadcast instrs
// per function vs round-1's 2-wave layout).
// ---------------------------------------------------------------------------
__global__ __launch_bounds__(128) void k1_attn(
    const int* __restrict__ v1i, const int* __restrict__ pti,
    const int* __restrict__ v2i,
    const float* __restrict__ vemb, const float* __restrict__ pemb,
    const float* __restrict__ Wfc, const float* __restrict__ bfc,
    const float* __restrict__ watt, const float* __restrict__ batt,
    unsigned short* __restrict__ vbf)
{
    const int w  = threadIdx.x >> 6;   // wave slot (function within block)
    const int ln = threadIdx.x & 63;
    const int b  = blockIdx.x * 2 + w;
    __shared__ float ctx[2][NREP][3 * EDIM];   // 30720 B

    // gather [10 x 384] context rows as float4 (96 float4 per n; no float4
    // crosses a 128-boundary since 128 % 4 == 0 and chunks are 32 float4s)
    const int base = b * NREP;
    #pragma unroll
    for (int j = 0; j < 15; ++j) {
        int i4 = j * 64 + ln;          // 0..959
        int n  = i4 / 96;
        int c4 = i4 - n * 96;          // 0..95
        int c  = c4 * 4;
        const float* src;
        if (c4 < 32)      src = vemb + (size_t)v1i[base + n] * EDIM + c;
        else if (c4 < 64) src = pemb + (size_t)pti[base + n] * EDIM + (c - 128);
        else              src = vemb + (size_t)v2i[base + n] * EDIM + (c - 256);
        *(float4*)&ctx[w][n][c] = *(const float4*)src;
    }
    __syncthreads();

    float acc0[NREP], acc1[NREP];
    #pragma unroll
    for (int n = 0; n < NREP; ++n) { acc0[n] = 0.f; acc1[n] = 0.f; }

    for (int k = 0; k < 384; k += 4) {
        float wa0 = Wfc[(k + 0) * EDIM + ln];
        float wa1 = Wfc[(k + 1) * EDIM + ln];
        float wa2 = Wfc[(k + 2) * EDIM + ln];
        float wa3 = Wfc[(k + 3) * EDIM + ln];
        float wb0 = Wfc[(k + 0) * EDIM + ln + 64];
        float wb1 = Wfc[(k + 1) * EDIM + ln + 64];
        float wb2 = Wfc[(k + 2) * EDIM + ln + 64];
        float wb3 = Wfc[(k + 3) * EDIM + ln + 64];
        #pragma unroll
        for (int n = 0; n < NREP; ++n) {
            float4 c4 = *(const float4*)&ctx[w][n][k];
            acc0[n] = fmaf(c4.x, wa0, acc0[n]);
            acc0[n] = fmaf(c4.y, wa1, acc0[n]);
            acc0[n] = fmaf(c4.z, wa2, acc0[n]);
            acc0[n] = fmaf(c4.w, wa3, acc0[n]);
            acc1[n] = fmaf(c4.x, wb0, acc1[n]);
            acc1[n] = fmaf(c4.y, wb1, acc1[n]);
            acc1[n] = fmaf(c4.z, wb2, acc1[n]);
            acc1[n] = fmaf(c4.w, wb3, acc1[n]);
        }
    }

    const float b0 = bfc[ln],       b1 = bfc[ln + 64];
    const float wat0 = watt[ln],    wat1 = watt[ln + 64];
    const float batt0 = batt[0];

    float ct0[NREP], ct1[NREP];
    #pragma unroll
    for (int n = 0; n < NREP; ++n) {
        ct0[n] = tanhf(acc0[n] + b0);
        ct1[n] = tanhf(acc1[n] + b1);
    }

    float a[NREP];
    float m = -1e30f;
    #pragma unroll
    for (int n = 0; n < NREP; ++n) {
        float p = ct0[n] * wat0 + ct1[n] * wat1;
        p += __shfl_xor(p, 32);
        p += __shfl_xor(p, 16);
        p += __shfl_xor(p, 8);
        p += __shfl_xor(p, 4);
        p += __shfl_xor(p, 2);
        p += __shfl_xor(p, 1);
        a[n] = p + batt0;
        m = fmaxf(m, a[n]);
    }
    float s = 0.f;
    #pragma unroll
    for (int n = 0; n < NREP; ++n) { a[n] = __expf(a[n] - m); s += a[n]; }
    const float inv = 1.f / s;

    float v0 = 0.f, v1 = 0.f;
    #pragma unroll
    for (int n = 0; n < NREP; ++n) {
        float at = a[n] * inv;
        v0 = fmaf(at, ct0[n], v0);
        v1 = fmaf(at, ct1[n], v1);
    }
    vbf[b * EDIM + ln]      = f2bf(v0);
    vbf[b * EDIM + ln + 64] = f2bf(v1);
}

// ---------------------------------------------------------------------------
// Kconv: tag_emb fp32 [VT,128] -> bf16 [NPAD,128], zero-padded rows
// ---------------------------------------------------------------------------
__global__ __launch_bounds__(256) void k_conv_tag(
    const float* __restrict__ tag, unsigned short* __restrict__ tbf)
{
    size_t i = ((size_t)blockIdx.x * 256 + threadIdx.x) * 4;
    if (i >= (size_t)NPAD * EDIM) return;
    float4 x = make_float4(0.f, 0.f, 0.f, 0.f);
    if (i < (size_t)VTAG * EDIM) x = *(const float4*)(tag + i);
    ushort4 o;
    o.x = f2bf(x.x); o.y = f2bf(x.y); o.z = f2bf(x.z); o.w = f2bf(x.w);
    *(ushort4*)(tbf + i) = o;
}

// ---------------------------------------------------------------------------
// Shared MFMA core: wave computes 32 rows x 64 cols of logits.
// block = 256 thr = 4 waves; grid = (B/128, NSTRIP).
// ---------------------------------------------------------------------------
__device__ __forceinline__ void mfma_logits(
    const unsigned short* __restrict__ vbf, const unsigned short* __restrict__ tbf,
    int rowbase, int n0, int quad, int l16, f32x4 acc[2][4])
{
    const bf16x8* tb8 = (const bf16x8*)tbf;  // unit = 16 B = 8 bf16
    const bf16x8* vb8 = (const bf16x8*)vbf;

    bf16x8 bfrag[4][4];
    #pragma unroll
    for (int nt = 0; nt < 4; ++nt) {
        int col = n0 + nt * 16 + l16;
        const bf16x8* p = tb8 + (size_t)col * 16 + quad;
        #pragma unroll
        for (int ks = 0; ks < 4; ++ks) bfrag[nt][ks] = p[ks * 4];
    }
    bf16x8 afrag[2][4];
    #pragma unroll
    for (int mt = 0; mt < 2; ++mt) {
        int row = rowbase + mt * 16 + l16;
        const bf16x8* p = vb8 + (size_t)row * 16 + quad;
        #pragma unroll
        for (int ks = 0; ks < 4; ++ks) afrag[mt][ks] = p[ks * 4];
    }

    #pragma unroll
    for (int mt = 0; mt < 2; ++mt)
        #pragma unroll
        for (int nt = 0; nt < 4; ++nt) acc[mt][nt] = (f32x4){0.f, 0.f, 0.f, 0.f};

    #pragma unroll
    for (int ks = 0; ks < 4; ++ks)
        #pragma unroll
        for (int mt = 0; mt < 2; ++mt)
            #pragma unroll
            for (int nt = 0; nt < 4; ++nt)
                acc[mt][nt] = __builtin_amdgcn_mfma_f32_16x16x32_bf16(
                    afrag[mt][ks], bfrag[nt][ks], acc[mt][nt], 0, 0, 0);
}

// ---------------------------------------------------------------------------
// K2a: per-strip max / sumexp partials ONLY — no logits write.
// ---------------------------------------------------------------------------
__global__ __launch_bounds__(256) void k2a_partials(
    const unsigned short* __restrict__ vbf, const unsigned short* __restrict__ tbf,
    float* __restrict__ pmax, float* __restrict__ psum)
{
    const int wave = threadIdx.x >> 6;
    const int lane = threadIdx.x & 63;
    const int quad = lane >> 4;
    const int l16  = lane & 15;
    const int strip = blockIdx.y;
    const int n0 = strip * 64;
    const int rowbase = blockIdx.x * 128 + wave * 32;

    f32x4 acc[2][4];
    mfma_logits(vbf, tbf, rowbase, n0, quad, l16, acc);

    #pragma unroll
    for (int mt = 0; mt < 2; ++mt) {
        #pragma unroll
        for (int r = 0; r < 4; ++r) {
            const int row = rowbase + mt * 16 + quad * 4 + r;
            float lm = -1e30f;
            #pragma unroll
            for (int nt = 0; nt < 4; ++nt) {
                int col = n0 + nt * 16 + l16;
                if (col < VTAG) lm = fmaxf(lm, acc[mt][nt][r]);
            }
            lm = fmaxf(lm, __shfl_xor(lm, 1));
            lm = fmaxf(lm, __shfl_xor(lm, 2));
            lm = fmaxf(lm, __shfl_xor(lm, 4));
            lm = fmaxf(lm, __shfl_xor(lm, 8));
            float ls = 0.f;
            #pragma unroll
            for (int nt = 0; nt < 4; ++nt) {
                int col = n0 + nt * 16 + l16;
                if (col < VTAG) ls += __expf(acc[mt][nt][r] - lm);
            }
            ls += __shfl_xor(ls, 1);
            ls += __shfl_xor(ls, 2);
            ls += __shfl_xor(ls, 4);
            ls += __shfl_xor(ls, 8);
            if (l16 == 0) {
                pmax[(size_t)row * NSTRIP + strip] = lm;
                psum[(size_t)row * NSTRIP + strip] = ls;
            }
        }
    }
}

// ---------------------------------------------------------------------------
// K3: reduce NSTRIP partials per row -> row max M and 1/S
// ---------------------------------------------------------------------------
__global__ __launch_bounds__(256) void k3_reduce(
    const float* __restrict__ pmax, const float* __restrict__ psum,
    float* __restrict__ rowM, float* __restrict__ rowR)
{
    const int row = blockIdx.x * 4 + (threadIdx.x >> 6);
    const int ln = threadIdx.x & 63;
    const float* pm = pmax + (size_t)row * NSTRIP;
    const float* ps = psum + (size_t)row * NSTRIP;

    float m = -1e30f;
    for (int i = ln; i < NSTRIP; i += 64) m = fmaxf(m, pm[i]);
    m = fmaxf(m, __shfl_xor(m, 32));
    m = fmaxf(m, __shfl_xor(m, 16));
    m = fmaxf(m, __shfl_xor(m, 8));
    m = fmaxf(m, __shfl_xor(m, 4));
    m = fmaxf(m, __shfl_xor(m, 2));
    m = fmaxf(m, __shfl_xor(m, 1));

    float s = 0.f;
    for (int i = ln; i < NSTRIP; i += 64) s += ps[i] * __expf(pm[i] - m);
    s += __shfl_xor(s, 32);
    s += __shfl_xor(s, 16);
    s += __shfl_xor(s, 8);
    s += __shfl_xor(s, 4);
    s += __shfl_xor(s, 2);
    s += __shfl_xor(s, 1);

    if (ln == 0) { rowM[row] = m; rowR[row] = 1.f / s; }
}

// ---------------------------------------------------------------------------
// K2b: recompute logits (identical MFMA), write q = exp(x - M) * R directly.
// ---------------------------------------------------------------------------
__global__ __launch_bounds__(256) void k2b_write(
    const unsigned short* __restrict__ vbf, const unsigned short* __restrict__ tbf,
    const float* __restrict__ rowM, const float* __restrict__ rowR,
    float* __restrict__ out)
{
    const int wave = threadIdx.x >> 6;
    const int lane = threadIdx.x & 63;
    const int quad = lane >> 4;
    const int l16  = lane & 15;
    const int strip = blockIdx.y;
    const int n0 = strip * 64;
    const int rowbase = blockIdx.x * 128 + wave * 32;

    f32x4 acc[2][4];
    mfma_logits(vbf, tbf, rowbase, n0, quad, l16, acc);

    #pragma unroll
    for (int mt = 0; mt < 2; ++mt) {
        #pragma unroll
        for (int r = 0; r < 4; ++r) {
            const int row = rowbase + mt * 16 + quad * 4 + r;
            const float M = rowM[row];
            const float R = rowR[row];
            #pragma unroll
            for (int nt = 0; nt < 4; ++nt) {
                int col = n0 + nt * 16 + l16;
                if (col < VTAG)
                    out[(size_t)row * VTAG + col] = __expf(acc[mt][nt][r] - M) * R;
            }
        }
    }
}

// ---------------------------------------------------------------------------
extern "C" void kernel_launch(void* const* d_in, const int* in_sizes, int n_in,
                              void* d_out, int out_size, void* d_ws, size_t ws_size,
                              hipStream_t stream)
{
    const int*   v1i  = (const int*)d_in[0];
    const int*   pti  = (const int*)d_in[1];
    const int*   v2i  = (const int*)d_in[2];
    const float* vemb = (const float*)d_in[3];
    const float* pemb = (const float*)d_in[4];
    const float* temb = (const float*)d_in[5];
    const float* Wfc  = (const float*)d_in[6];
    const float* bfc  = (const float*)d_in[7];
    const float* watt = (const float*)d_in[8];
    const float* batt = (const float*)d_in[9];
    float* out = (float*)d_out;

    char* ws = (char*)d_ws;
    const size_t vbf_off  = 0;                                   // 2048*128*2   = 524288
    const size_t tbf_off  = vbf_off + 524288;                    // 50304*128*2  = 12877824
    const size_t pmax_off = tbf_off + 12877824;                  // 2048*786*4   = 6438912
    const size_t psum_off = pmax_off + 6438912;
    const size_t rowm_off = psum_off + 6438912;
    const size_t rowr_off = rowm_off + 8192;

    unsigned short* vbf = (unsigned short*)(ws + vbf_off);
    unsigned short* tbf = (unsigned short*)(ws + tbf_off);
    float* pmax = (float*)(ws + pmax_off);
    float* psum = (float*)(ws + psum_off);
    float* rowM = (float*)(ws + rowm_off);
    float* rowR = (float*)(ws + rowr_off);

    hipLaunchKernelGGL(k1_attn, dim3(BFUNC / 2), dim3(128), 0, stream,
                       v1i, pti, v2i, vemb, pemb, Wfc, bfc, watt, batt, vbf);
    hipLaunchKernelGGL(k_conv_tag, dim3((NPAD * EDIM / 4 + 255) / 256), dim3(256),
                       0, stream, temb, tbf);
    hipLaunchKernelGGL(k2a_partials, dim3(BFUNC / 128, NSTRIP), dim3(256), 0, stream,
                       vbf, tbf, pmax, psum);
    hipLaunchKernelGGL(k3_reduce, dim3(BFUNC / 4), dim3(256), 0, stream,
                       pmax, psum, rowM, rowR);
    hipLaunchKernelGGL(k2b_write, dim3(BFUNC / 128, NSTRIP), dim3(256), 0, stream,
                       vbf, tbf, rowM, rowR, out);
}